// Round 6
// baseline (774.775 us; speedup 1.0000x reference)
//
#include <hip/hip_runtime.h>
#include <hip/hip_bf16.h>
#include <stdint.h>

// x[65536][256] f32, memory[2048][256] f32
// out = [ memory_output[65536][256] | attention_weights[65536][2048] ] f32
#define NQ 65536
#define MM 2048
#define DD 256

typedef __bf16 bf16x8 __attribute__((ext_vector_type(8)));
typedef float f32x16 __attribute__((ext_vector_type(16)));
typedef unsigned short u16;
typedef unsigned int u32;
typedef u16 u16x8 __attribute__((ext_vector_type(8)));

__device__ __forceinline__ u16 f32_to_bf16_rtne(float v) {
  u32 u = __builtin_bit_cast(u32, v);
  u += 0x7FFFu + ((u >> 16) & 1u);
  return (u16)(u >> 16);
}

// memb: row-major [2048][256] bf16; memT: row-major [256][2048] bf16.
// Both are L2-resident (1 MB each) — passes read fragments directly from
// global, no LDS staging, no barriers.
__global__ __launch_bounds__(256) void mem_convert_kernel(
    const float* __restrict__ memory, u16* __restrict__ memb,
    u16* __restrict__ memT) {
  int tid = blockIdx.x * 256 + threadIdx.x;  // 524288 total
  u16 b = f32_to_bf16_rtne(memory[tid]);
  memb[tid] = b;
  int m = tid >> 8, d = tid & 255;
  memT[(size_t)d * MM + m] = b;
}

// ---- Pass 1 (barrier-free): QK + exp -> unnormalized e + row sums ----
// 512 blocks x 4 waves x 32q. B-frags read directly from memb; values and
// lane layout identical to the R2/R5-validated LDS path (swizzle+inverse
// cancel). e stored with identity [row][col] addressing (R5-validated).
template <bool STORE_BF16>
__global__ __launch_bounds__(256, 2) void pass1_kernel(
    const float* __restrict__ x, const u16* __restrict__ memb,
    u16* __restrict__ p_e, float* __restrict__ outWf,
    float* __restrict__ sums) {
  const int tid = threadIdx.x;
  const int wv = tid >> 6;
  const int l = tid & 63;
  const int q5 = l & 31;
  const int h = l >> 5;
  const int qw = blockIdx.x * 128 + wv * 32;

  bf16x8 aq[16];
  {
    const float* xrow = x + (size_t)(qw + q5) * DD;
#pragma unroll
    for (int ks = 0; ks < 16; ++ks) {
      const float4 f0 = *(const float4*)(xrow + ks * 16 + h * 8);
      const float4 f1 = *(const float4*)(xrow + ks * 16 + h * 8 + 4);
      bf16x8 a;
      a[0] = (__bf16)f0.x; a[1] = (__bf16)f0.y;
      a[2] = (__bf16)f0.z; a[3] = (__bf16)f0.w;
      a[4] = (__bf16)f1.x; a[5] = (__bf16)f1.y;
      a[6] = (__bf16)f1.z; a[7] = (__bf16)f1.w;
      aq[ks] = a;
    }
  }

  float part[16];
#pragma unroll
  for (int r = 0; r < 16; ++r) part[r] = 0.f;

  for (int tm = 0; tm < 64; ++tm) {
    // lane's B row: m = tm*32 + q5; k-chunk = ks*16 + h*8 (16B contiguous)
    const u16* brow = memb + (((size_t)(tm * 32 + q5)) << 8) + h * 8;
    f32x16 acc = 0.f;
    __builtin_amdgcn_s_setprio(1);
#pragma unroll
    for (int ks = 0; ks < 16; ++ks) {
      bf16x8 b = *(const bf16x8*)(brow + ks * 16);
      acc = __builtin_amdgcn_mfma_f32_32x32x16_bf16(aq[ks], b, acc, 0, 0, 0);
    }
    __builtin_amdgcn_s_setprio(0);
#pragma unroll
    for (int r = 0; r < 16; ++r) {
      const int qrow = (r & 3) + 8 * (r >> 2) + 4 * h;
      const float e = __expf(acc[r]);
      part[r] += e;
      if (STORE_BF16) {
        p_e[(size_t)(qw + qrow) * MM + tm * 32 + q5] = f32_to_bf16_rtne(e);
      } else {
        outWf[(size_t)(qw + qrow) * MM + tm * 32 + q5] = e;
      }
    }
  }

#pragma unroll
  for (int r = 0; r < 16; ++r) {
    float p = part[r];
    p += __shfl_xor(p, 1, 64);
    p += __shfl_xor(p, 2, 64);
    p += __shfl_xor(p, 4, 64);
    p += __shfl_xor(p, 8, 64);
    p += __shfl_xor(p, 16, 64);
    if (q5 == 0) sums[qw + (r & 3) + 8 * (r >> 2) + 4 * h] = p;
  }
}

// ---- Pass 2 (barrier-free): W = e*inv + O = (e*M)*inv ----
// 512 blocks x 4 waves x 32q. PA = raw stored bf16 bits (unnormalized);
// B-frags read directly from memT (de-swizzled image of the validated
// LDS reads); O scaled at the end by invr (R3/R5-validated).
template <bool LOAD_BF16>
__global__ __launch_bounds__(256, 2) void pass2_kernel(
    const u16* __restrict__ p_e, const u16* __restrict__ memT,
    const float* __restrict__ sums, float* __restrict__ outO,
    float* __restrict__ outW) {
  const int tid = threadIdx.x;
  const int wv = tid >> 6;
  const int l = tid & 63;
  const int q5 = l & 31;
  const int h = l >> 5;
  const int qw = blockIdx.x * 128 + wv * 32;

  const float inv_lane = 1.0f / sums[qw + q5];
  float invr[16];
#pragma unroll
  for (int r = 0; r < 16; ++r) {
    invr[r] = __shfl(inv_lane, (r & 3) + 8 * (r >> 2) + 4 * h, 64);
  }

  f32x16 oacc[8];
#pragma unroll
  for (int i = 0; i < 8; ++i) oacc[i] = 0.f;

  for (int tm = 0; tm < 64; ++tm) {
    bf16x8 pa[2];
    if (LOAD_BF16) {
      const u16* prow = p_e + (size_t)(qw + q5) * MM + tm * 32;
#pragma unroll
      for (int ks2 = 0; ks2 < 2; ++ks2) {
        u16x8 pe = *(const u16x8*)(prow + ks2 * 16 + h * 8);
        pa[ks2] = __builtin_bit_cast(bf16x8, pe);  // unnormalized e
        float w[8];
#pragma unroll
        for (int j = 0; j < 8; ++j) {
          w[j] = __builtin_bit_cast(float, (u32)pe[j] << 16) * inv_lane;
        }
        float* base =
            outW + (size_t)(qw + q5) * MM + tm * 32 + ks2 * 16 + h * 8;
        *(float4*)base = make_float4(w[0], w[1], w[2], w[3]);
        *(float4*)(base + 4) = make_float4(w[4], w[5], w[6], w[7]);
      }
    } else {
      float* wrow = outW + (size_t)(qw + q5) * MM + tm * 32;
#pragma unroll
      for (int ks2 = 0; ks2 < 2; ++ks2) {
        float4 f0 = *(const float4*)(wrow + ks2 * 16 + h * 8);
        float4 f1 = *(const float4*)(wrow + ks2 * 16 + h * 8 + 4);
        float w0 = f0.x * inv_lane, w1 = f0.y * inv_lane;
        float w2 = f0.z * inv_lane, w3 = f0.w * inv_lane;
        float w4 = f1.x * inv_lane, w5 = f1.y * inv_lane;
        float w6 = f1.z * inv_lane, w7 = f1.w * inv_lane;
        *(float4*)(wrow + ks2 * 16 + h * 8) = make_float4(w0, w1, w2, w3);
        *(float4*)(wrow + ks2 * 16 + h * 8 + 4) = make_float4(w4, w5, w6, w7);
        bf16x8 p;
        p[0] = (__bf16)w0; p[1] = (__bf16)w1; p[2] = (__bf16)w2;
        p[3] = (__bf16)w3; p[4] = (__bf16)w4; p[5] = (__bf16)w5;
        p[6] = (__bf16)w6; p[7] = (__bf16)w7;
        pa[ks2] = p;
      }
    }

    // lane's B row for dsub: d = dsub*32 + q5; k-chunk = ks2*16 + h*8
    const u16* tbase = memT + (size_t)q5 * MM + tm * 32 + h * 8;
    __builtin_amdgcn_s_setprio(1);
#pragma unroll
    for (int ks2 = 0; ks2 < 2; ++ks2) {
#pragma unroll
      for (int dsub = 0; dsub < 8; ++dsub) {
        bf16x8 b =
            *(const bf16x8*)(tbase + (size_t)dsub * 32 * MM + ks2 * 16);
        oacc[dsub] =
            __builtin_amdgcn_mfma_f32_32x32x16_bf16(pa[ks2], b, oacc[dsub], 0,
                                                    0, 0);
      }
    }
    __builtin_amdgcn_s_setprio(0);
  }

#pragma unroll
  for (int dsub = 0; dsub < 8; ++dsub) {
#pragma unroll
    for (int r = 0; r < 16; ++r) {
      const int qrow = (r & 3) + 8 * (r >> 2) + 4 * h;
      const float scale = LOAD_BF16 ? invr[r] : 1.0f;
      outO[(size_t)(qw + qrow) * DD + dsub * 32 + q5] = oacc[dsub][r] * scale;
    }
  }
}

extern "C" void kernel_launch(void* const* d_in, const int* in_sizes, int n_in,
                              void* d_out, int out_size, void* d_ws,
                              size_t ws_size, hipStream_t stream) {
  const float* x = (const float*)d_in[0];
  const float* memory = (const float*)d_in[1];
  float* outO = (float*)d_out;           // [65536][256]
  float* outW = outO + (size_t)NQ * DD;  // [65536][2048]

  // ws layout: memb (1MB) | memT (1MB) | sums (256KB) | p_e (256MB bf16)
  u16* memb = (u16*)d_ws;
  u16* memT = memb + (size_t)MM * DD;
  float* sums = (float*)(memT + (size_t)MM * DD);
  u16* p_e = (u16*)(sums + NQ);
  const size_t need = (size_t)MM * DD * 2 * 2 + (size_t)NQ * 4 +
                      (size_t)NQ * MM * 2;  // ~258.25 MB

  mem_convert_kernel<<<dim3((MM * DD) / 256), dim3(256), 0, stream>>>(
      memory, memb, memT);
  if (ws_size >= need) {
    pass1_kernel<true><<<dim3(NQ / 128), dim3(256), 0, stream>>>(
        x, memb, p_e, outW, sums);
    pass2_kernel<true><<<dim3(NQ / 128), dim3(256), 0, stream>>>(
        p_e, memT, sums, outO, outW);
  } else {
    pass1_kernel<false><<<dim3(NQ / 128), dim3(256), 0, stream>>>(
        x, memb, p_e, outW, sums);
    pass2_kernel<false><<<dim3(NQ / 128), dim3(256), 0, stream>>>(
        p_e, memT, sums, outO, outW);
  }
}

// Round 7
// 540.926 us; speedup vs baseline: 1.4323x; 1.4323x over previous
//
#include <hip/hip_runtime.h>
#include <hip/hip_bf16.h>
#include <stdint.h>

// x[65536][256] f32, memory[2048][256] f32
// out = [ memory_output[65536][256] | attention_weights[65536][2048] ] f32
#define NQ 65536
#define MM 2048
#define DD 256

typedef __bf16 bf16x8 __attribute__((ext_vector_type(8)));
typedef float f32x16 __attribute__((ext_vector_type(16)));
typedef unsigned short u16;
typedef unsigned int u32;
typedef u16 u16x8 __attribute__((ext_vector_type(8)));

typedef __attribute__((address_space(3))) u32 lds_u32;
typedef __attribute__((address_space(1))) u32 glb_u32;

#define GLOAD16(gsrc, ldst)                                                    \
  __builtin_amdgcn_global_load_lds((glb_u32*)(uintptr_t)(gsrc),                \
                                   (lds_u32*)(u32)(uintptr_t)(ldst), 16, 0, 0)

__device__ __forceinline__ u16 f32_to_bf16_rtne(float v) {
  u32 u = __builtin_bit_cast(u32, v);
  u += 0x7FFFu + ((u >> 16) & 1u);
  return (u16)(u >> 16);
}

// memb: row-major [2048][256] bf16.
// memTswz: per 32-m tile t (64 tiles, 16KB each):
//   u16 idx = t*8192 + (d*4 + slot)*8 + e, slot = c ^ ((d>>1)&3),
//   within-tile m = c*8 + e. (R5-validated staging + PV read path.)
__global__ __launch_bounds__(256) void mem_convert_kernel(
    const float* __restrict__ memory, u16* __restrict__ memb,
    u16* __restrict__ memTswz) {
  int tid = blockIdx.x * 256 + threadIdx.x;  // 524288 total
  u16 b = f32_to_bf16_rtne(memory[tid]);
  memb[tid] = b;
  int m = tid >> 8, d = tid & 255;
  int t = m >> 5, mi = m & 31;
  int c = mi >> 3, e = mi & 7;
  int slot = c ^ ((d >> 1) & 3);
  memTswz[(size_t)t * 8192 + (size_t)(d * 4 + slot) * 8 + e] = b;
}

// ---- Pass 1 (main): QK + exp -> bf16 e + sums. 1024 blocks x 4 waves.
// Wave (g,p): q-rows [bid*64+g*32, +32), m-half p of each staged 64-row
// tile. Single 32KB buffer, 2 barriers/step, 32 steps. All address paths
// identical to the R5-validated kernel.
__global__ __launch_bounds__(256, 4) void pass1_kernel(
    const float* __restrict__ x, const u16* __restrict__ memb,
    u16* __restrict__ p_e, float* __restrict__ sums) {
  __shared__ __align__(16) char stage[32768];
  __shared__ float lsum[2][2][32];

  const int tid = threadIdx.x;
  const int wv = tid >> 6;
  const int g = wv >> 1;   // q-group
  const int p = wv & 1;    // m-half
  const int l = tid & 63;
  const int q5 = l & 31;
  const int h = l >> 5;
  const int qw = blockIdx.x * 64 + g * 32;

  bf16x8 aq[16];
  {
    const float* xrow = x + (size_t)(qw + q5) * DD;
#pragma unroll
    for (int ks = 0; ks < 16; ++ks) {
      const float4 f0 = *(const float4*)(xrow + ks * 16 + h * 8);
      const float4 f1 = *(const float4*)(xrow + ks * 16 + h * 8 + 4);
      bf16x8 a;
      a[0] = (__bf16)f0.x; a[1] = (__bf16)f0.y;
      a[2] = (__bf16)f0.z; a[3] = (__bf16)f0.w;
      a[4] = (__bf16)f1.x; a[5] = (__bf16)f1.y;
      a[6] = (__bf16)f1.z; a[7] = (__bf16)f1.w;
      aq[ks] = a;
    }
  }

  float part[16];
#pragma unroll
  for (int r = 0; r < 16; ++r) part[r] = 0.f;

  for (int t = 0; t < 32; ++t) {
    // stage 64 mem rows [t*64, +64) -> 32KB (32 chunks of 1KB)
#pragma unroll
    for (int i = 0; i < 8; ++i) {
      const int wc = wv * 8 + i;
      const int row = wc * 2 + h;
      const int csrc = q5 ^ (row & 7);
      GLOAD16(memb + (((size_t)(t * 64 + row)) << 8) + csrc * 8,
              stage + (wc << 10));
    }
    __syncthreads();  // staged data visible

    const int mrow = p * 32 + q5;
    const char* bbase = stage + mrow * 512;
    const int sw = mrow & 7;
    f32x16 acc = 0.f;
    __builtin_amdgcn_s_setprio(1);
#pragma unroll
    for (int ks = 0; ks < 16; ++ks) {
      bf16x8 b = *(const bf16x8*)(bbase + (((ks * 2 + h) ^ sw) << 4));
      acc = __builtin_amdgcn_mfma_f32_32x32x16_bf16(aq[ks], b, acc, 0, 0, 0);
    }
    __builtin_amdgcn_s_setprio(0);
    const int tm = t * 2 + p;
#pragma unroll
    for (int r = 0; r < 16; ++r) {
      const int qrow = (r & 3) + 8 * (r >> 2) + 4 * h;
      const float e = __expf(acc[r]);
      part[r] += e;
      p_e[(size_t)(qw + qrow) * MM + tm * 32 + q5] = f32_to_bf16_rtne(e);
    }
    __syncthreads();  // all reads done before next overwrite
  }

  // reduce rowsums across the 32 m-lanes, then across the two m-half waves
#pragma unroll
  for (int r = 0; r < 16; ++r) {
    float s = part[r];
    s += __shfl_xor(s, 1, 64);
    s += __shfl_xor(s, 2, 64);
    s += __shfl_xor(s, 4, 64);
    s += __shfl_xor(s, 8, 64);
    s += __shfl_xor(s, 16, 64);
    part[r] = s;
  }
  if (q5 == 0) {
#pragma unroll
    for (int r = 0; r < 16; ++r) {
      lsum[g][p][(r & 3) + 8 * (r >> 2) + 4 * h] = part[r];
    }
  }
  __syncthreads();
  if (p == 0 && q5 == 0) {
#pragma unroll
    for (int r = 0; r < 16; ++r) {
      const int qrow = (r & 3) + 8 * (r >> 2) + 4 * h;
      sums[qw + qrow] = lsum[g][0][qrow] + lsum[g][1][qrow];
    }
  }
}

// ---- Pass 2 (main): W = e*inv + O = (e*M)*inv. 1024 blocks x 4 waves.
// Wave (g,dh): q-rows [bid*64+g*32, +32), d-half dh (dsub dh*4..+4).
// oacc shrinks to 4 frags; W written by dh==0 wave only. Paths = R5.
__global__ __launch_bounds__(256, 4) void pass2_kernel(
    const u16* __restrict__ p_e, const u16* __restrict__ memTswz,
    const float* __restrict__ sums, float* __restrict__ outO,
    float* __restrict__ outW) {
  __shared__ __align__(16) char tstage[2][16384];

  const int tid = threadIdx.x;
  const int wv = tid >> 6;
  const int g = wv >> 1;   // q-group
  const int dh = wv & 1;   // d-half
  const int l = tid & 63;
  const int q5 = l & 31;
  const int h = l >> 5;
  const int qw = blockIdx.x * 64 + g * 32;

  const float inv_lane = 1.0f / sums[qw + q5];
  float invr[16];
#pragma unroll
  for (int r = 0; r < 16; ++r) {
    invr[r] = __shfl(inv_lane, (r & 3) + 8 * (r >> 2) + 4 * h, 64);
  }

  auto STAGE = [&](int t, char* buf) {  // 16KB memT tile, linear
#pragma unroll
    for (int i = 0; i < 4; ++i) {
      const int ci = wv * 4 + i;
      GLOAD16(memTswz + ((size_t)t * 1024 + ci * 64 + l) * 8, buf + (ci << 10));
    }
  };

  f32x16 oacc[4];
#pragma unroll
  for (int i = 0; i < 4; ++i) oacc[i] = 0.f;

  STAGE(0, tstage[0]);
  __syncthreads();
  for (int tm = 0; tm < 64; ++tm) {
    char* cur = tstage[tm & 1];
    char* nxt = tstage[(tm & 1) ^ 1];
    if (tm + 1 < 64) STAGE(tm + 1, nxt);

    bf16x8 pa[2];
    const u16* prow = p_e + (size_t)(qw + q5) * MM + tm * 32;
#pragma unroll
    for (int ks2 = 0; ks2 < 2; ++ks2) {
      u16x8 pe = *(const u16x8*)(prow + ks2 * 16 + h * 8);
      pa[ks2] = __builtin_bit_cast(bf16x8, pe);  // unnormalized e
      if (dh == 0) {
        float w[8];
#pragma unroll
        for (int j = 0; j < 8; ++j) {
          w[j] = __builtin_bit_cast(float, (u32)pe[j] << 16) * inv_lane;
        }
        float* base =
            outW + (size_t)(qw + q5) * MM + tm * 32 + ks2 * 16 + h * 8;
        *(float4*)base = make_float4(w[0], w[1], w[2], w[3]);
        *(float4*)(base + 4) = make_float4(w[4], w[5], w[6], w[7]);
      }
    }

    __builtin_amdgcn_s_setprio(1);
#pragma unroll
    for (int ks2 = 0; ks2 < 2; ++ks2) {
#pragma unroll
      for (int i = 0; i < 4; ++i) {
        const int d = (dh * 4 + i) * 32 + q5;
        const int slot = (2 * ks2 + h) ^ ((d >> 1) & 3);
        bf16x8 b = *(const bf16x8*)(cur + d * 64 + slot * 16);
        oacc[i] =
            __builtin_amdgcn_mfma_f32_32x32x16_bf16(pa[ks2], b, oacc[i], 0, 0,
                                                    0);
      }
    }
    __builtin_amdgcn_s_setprio(0);
    __syncthreads();
  }

#pragma unroll
  for (int i = 0; i < 4; ++i) {
#pragma unroll
    for (int r = 0; r < 16; ++r) {
      const int qrow = (r & 3) + 8 * (r >> 2) + 4 * h;
      outO[(size_t)(qw + qrow) * DD + (dh * 4 + i) * 32 + q5] =
          oacc[i][r] * invr[r];
    }
  }
}

// ---- Fallback (ws too small): R5 f32-roundtrip kernels, verbatim ----
__global__ __launch_bounds__(256, 2) void pass1_fb(
    const float* __restrict__ x, const u16* __restrict__ memb,
    float* __restrict__ outWf, float* __restrict__ sums) {
  __shared__ __align__(16) char stage[2][32768];
  const int tid = threadIdx.x;
  const int wv = tid >> 6;
  const int l = tid & 63;
  const int q5 = l & 31;
  const int h = l >> 5;
  const int qw = blockIdx.x * 128 + wv * 32;

  bf16x8 aq[16];
  {
    const float* xrow = x + (size_t)(qw + q5) * DD;
#pragma unroll
    for (int ks = 0; ks < 16; ++ks) {
      const float4 f0 = *(const float4*)(xrow + ks * 16 + h * 8);
      const float4 f1 = *(const float4*)(xrow + ks * 16 + h * 8 + 4);
      bf16x8 a;
      a[0] = (__bf16)f0.x; a[1] = (__bf16)f0.y;
      a[2] = (__bf16)f0.z; a[3] = (__bf16)f0.w;
      a[4] = (__bf16)f1.x; a[5] = (__bf16)f1.y;
      a[6] = (__bf16)f1.z; a[7] = (__bf16)f1.w;
      aq[ks] = a;
    }
  }
  auto STAGE1 = [&](int mt, char* buf) {
#pragma unroll
    for (int i = 0; i < 8; ++i) {
      const int wc = wv * 8 + i;
      const int row = wc * 2 + h;
      const int csrc = q5 ^ (row & 7);
      GLOAD16(memb + (((size_t)(mt * 64 + row)) << 8) + csrc * 8,
              buf + (wc << 10));
    }
  };
  float part[16];
#pragma unroll
  for (int r = 0; r < 16; ++r) part[r] = 0.f;
  STAGE1(0, stage[0]);
  __syncthreads();
  for (int mt = 0; mt < 32; ++mt) {
    char* cur = stage[mt & 1];
    char* nxt = stage[(mt & 1) ^ 1];
    if (mt + 1 < 32) STAGE1(mt + 1, nxt);
#pragma unroll
    for (int msub = 0; msub < 2; ++msub) {
      const int mrow = msub * 32 + q5;
      const char* bbase = cur + mrow * 512;
      const int sw = mrow & 7;
      f32x16 acc = 0.f;
#pragma unroll
      for (int ks = 0; ks < 16; ++ks) {
        bf16x8 b = *(const bf16x8*)(bbase + (((ks * 2 + h) ^ sw) << 4));
        acc = __builtin_amdgcn_mfma_f32_32x32x16_bf16(aq[ks], b, acc, 0, 0, 0);
      }
      const int tm = mt * 2 + msub;
#pragma unroll
      for (int r = 0; r < 16; ++r) {
        const int qrow = (r & 3) + 8 * (r >> 2) + 4 * h;
        const float e = __expf(acc[r]);
        part[r] += e;
        outWf[(size_t)(qw + qrow) * MM + tm * 32 + q5] = e;
      }
    }
    __syncthreads();
  }
#pragma unroll
  for (int r = 0; r < 16; ++r) {
    float s = part[r];
    s += __shfl_xor(s, 1, 64);
    s += __shfl_xor(s, 2, 64);
    s += __shfl_xor(s, 4, 64);
    s += __shfl_xor(s, 8, 64);
    s += __shfl_xor(s, 16, 64);
    if (q5 == 0) sums[qw + (r & 3) + 8 * (r >> 2) + 4 * h] = s;
  }
}

__global__ __launch_bounds__(256, 2) void pass2_fb(
    const u16* __restrict__ memTswz, const float* __restrict__ sums,
    float* __restrict__ outO, float* __restrict__ outW) {
  __shared__ __align__(16) char tstage[2][16384];
  const int tid = threadIdx.x;
  const int wv = tid >> 6;
  const int l = tid & 63;
  const int q5 = l & 31;
  const int h = l >> 5;
  const int qw = blockIdx.x * 128 + wv * 32;
  const float inv_lane = 1.0f / sums[qw + q5];
  auto STAGE = [&](int t, char* buf) {
#pragma unroll
    for (int i = 0; i < 4; ++i) {
      const int ci = wv * 4 + i;
      GLOAD16(memTswz + ((size_t)t * 1024 + ci * 64 + l) * 8, buf + (ci << 10));
    }
  };
  f32x16 oacc[8];
#pragma unroll
  for (int i = 0; i < 8; ++i) oacc[i] = 0.f;
  STAGE(0, tstage[0]);
  __syncthreads();
  for (int tm = 0; tm < 64; ++tm) {
    char* cur = tstage[tm & 1];
    char* nxt = tstage[(tm & 1) ^ 1];
    if (tm + 1 < 64) STAGE(tm + 1, nxt);
    float* wrow = outW + (size_t)(qw + q5) * MM + tm * 32;
    bf16x8 pa[2];
#pragma unroll
    for (int ks2 = 0; ks2 < 2; ++ks2) {
      float4 f0 = *(const float4*)(wrow + ks2 * 16 + h * 8);
      float4 f1 = *(const float4*)(wrow + ks2 * 16 + h * 8 + 4);
      float w0 = f0.x * inv_lane, w1 = f0.y * inv_lane;
      float w2 = f0.z * inv_lane, w3 = f0.w * inv_lane;
      float w4 = f1.x * inv_lane, w5 = f1.y * inv_lane;
      float w6 = f1.z * inv_lane, w7 = f1.w * inv_lane;
      *(float4*)(wrow + ks2 * 16 + h * 8) = make_float4(w0, w1, w2, w3);
      *(float4*)(wrow + ks2 * 16 + h * 8 + 4) = make_float4(w4, w5, w6, w7);
      bf16x8 p;
      p[0] = (__bf16)w0; p[1] = (__bf16)w1; p[2] = (__bf16)w2;
      p[3] = (__bf16)w3; p[4] = (__bf16)w4; p[5] = (__bf16)w5;
      p[6] = (__bf16)w6; p[7] = (__bf16)w7;
      pa[ks2] = p;
    }
#pragma unroll
    for (int ks2 = 0; ks2 < 2; ++ks2) {
#pragma unroll
      for (int dsub = 0; dsub < 8; ++dsub) {
        const int d = dsub * 32 + q5;
        const int slot = (2 * ks2 + h) ^ ((d >> 1) & 3);
        bf16x8 b = *(const bf16x8*)(cur + d * 64 + slot * 16);
        oacc[dsub] =
            __builtin_amdgcn_mfma_f32_32x32x16_bf16(pa[ks2], b, oacc[dsub], 0,
                                                    0, 0);
      }
    }
    __syncthreads();
  }
#pragma unroll
  for (int dsub = 0; dsub < 8; ++dsub) {
#pragma unroll
    for (int r = 0; r < 16; ++r) {
      const int qrow = (r & 3) + 8 * (r >> 2) + 4 * h;
      outO[(size_t)(qw + qrow) * DD + dsub * 32 + q5] = oacc[dsub][r];
    }
  }
}

extern "C" void kernel_launch(void* const* d_in, const int* in_sizes, int n_in,
                              void* d_out, int out_size, void* d_ws,
                              size_t ws_size, hipStream_t stream) {
  const float* x = (const float*)d_in[0];
  const float* memory = (const float*)d_in[1];
  float* outO = (float*)d_out;           // [65536][256]
  float* outW = outO + (size_t)NQ * DD;  // [65536][2048]

  // ws layout: memb (1MB) | memTswz (1MB) | sums (256KB) | p_e (256MB bf16)
  u16* memb = (u16*)d_ws;
  u16* memTswz = memb + (size_t)MM * DD;
  float* sums = (float*)(memTswz + (size_t)MM * DD);
  u16* p_e = (u16*)(sums + NQ);
  const size_t need = (size_t)MM * DD * 2 * 2 + (size_t)NQ * 4 +
                      (size_t)NQ * MM * 2;  // ~258.25 MB

  mem_convert_kernel<<<dim3((MM * DD) / 256), dim3(256), 0, stream>>>(
      memory, memb, memTswz);
  if (ws_size >= need) {
    pass1_kernel<<<dim3(NQ / 64), dim3(256), 0, stream>>>(x, memb, p_e, sums);
    pass2_kernel<<<dim3(NQ / 64), dim3(256), 0, stream>>>(p_e, memTswz, sums,
                                                          outO, outW);
  } else {
    pass1_fb<<<dim3(NQ / 128), dim3(256), 0, stream>>>(x, memb, outW, sums);
    pass2_fb<<<dim3(NQ / 128), dim3(256), 0, stream>>>(memTswz, sums, outO,
                                                       outW);
  }
}

// Round 8
// 406.360 us; speedup vs baseline: 1.9066x; 1.3311x over previous
//
#include <hip/hip_runtime.h>
#include <hip/hip_bf16.h>
#include <stdint.h>

// x[65536][256] f32, memory[2048][256] f32
// out = [ memory_output[65536][256] | attention_weights[65536][2048] ] f32
#define NQ 65536
#define MM 2048
#define DD 256

typedef __bf16 bf16x8 __attribute__((ext_vector_type(8)));
typedef float f32x16 __attribute__((ext_vector_type(16)));
typedef unsigned short u16;
typedef unsigned int u32;
typedef u16 u16x8 __attribute__((ext_vector_type(8)));

typedef __attribute__((address_space(3))) u32 lds_u32;
typedef __attribute__((address_space(1))) u32 glb_u32;

#define GLOAD16(gsrc, ldst)                                                    \
  __builtin_amdgcn_global_load_lds((glb_u32*)(uintptr_t)(gsrc),                \
                                   (lds_u32*)(u32)(uintptr_t)(ldst), 16, 0, 0)

__device__ __forceinline__ u16 f32_to_bf16_rtne(float v) {
  u32 u = __builtin_bit_cast(u32, v);
  u += 0x7FFFu + ((u >> 16) & 1u);
  return (u16)(u >> 16);
}

// memb: row-major [2048][256] bf16.
// memTswz: per 32-m tile t (64 tiles, 16KB each):
//   u16 idx = t*8192 + (d*4 + slot)*8 + e, slot = c ^ ((d>>1)&3),
//   within-tile m = c*8 + e. (R5-validated staging + PV read path.)
__global__ __launch_bounds__(256) void mem_convert_kernel(
    const float* __restrict__ memory, u16* __restrict__ memb,
    u16* __restrict__ memTswz) {
  int tid = blockIdx.x * 256 + threadIdx.x;  // 524288 total
  u16 b = f32_to_bf16_rtne(memory[tid]);
  memb[tid] = b;
  int m = tid >> 8, d = tid & 255;
  int t = m >> 5, mi = m & 31;
  int c = mi >> 3, e = mi & 7;
  int slot = c ^ ((d >> 1) & 3);
  memTswz[(size_t)t * 8192 + (size_t)(d * 4 + slot) * 8 + e] = b;
}

// ---- Pass 1 (R5 verbatim): QK + exp -> bf16 e + sums ----
// 512 blocks x 4 waves x 32q; dbuf 2x32KB, 1 barrier per 64-row tile.
__global__ __launch_bounds__(256, 2) void pass1_kernel(
    const float* __restrict__ x, const u16* __restrict__ memb,
    u16* __restrict__ p_e, float* __restrict__ sums) {
  __shared__ __align__(16) char stage[2][32768];

  const int tid = threadIdx.x;
  const int wv = tid >> 6;
  const int l = tid & 63;
  const int q5 = l & 31;
  const int h = l >> 5;
  const int qw = blockIdx.x * 128 + wv * 32;

  bf16x8 aq[16];
  {
    const float* xrow = x + (size_t)(qw + q5) * DD;
#pragma unroll
    for (int ks = 0; ks < 16; ++ks) {
      const float4 f0 = *(const float4*)(xrow + ks * 16 + h * 8);
      const float4 f1 = *(const float4*)(xrow + ks * 16 + h * 8 + 4);
      bf16x8 a;
      a[0] = (__bf16)f0.x; a[1] = (__bf16)f0.y;
      a[2] = (__bf16)f0.z; a[3] = (__bf16)f0.w;
      a[4] = (__bf16)f1.x; a[5] = (__bf16)f1.y;
      a[6] = (__bf16)f1.z; a[7] = (__bf16)f1.w;
      aq[ks] = a;
    }
  }

  auto STAGE1 = [&](int mt, char* buf) {  // 64 mem rows -> 32KB
#pragma unroll
    for (int i = 0; i < 8; ++i) {
      const int wc = wv * 8 + i;
      const int row = wc * 2 + h;
      const int csrc = q5 ^ (row & 7);
      GLOAD16(memb + (((size_t)(mt * 64 + row)) << 8) + csrc * 8,
              buf + (wc << 10));
    }
  };

  float part[16];
#pragma unroll
  for (int r = 0; r < 16; ++r) part[r] = 0.f;

  STAGE1(0, stage[0]);
  __syncthreads();
  for (int mt = 0; mt < 32; ++mt) {
    char* cur = stage[mt & 1];
    char* nxt = stage[(mt & 1) ^ 1];
    if (mt + 1 < 32) STAGE1(mt + 1, nxt);
#pragma unroll
    for (int msub = 0; msub < 2; ++msub) {
      const int mrow = msub * 32 + q5;
      const char* bbase = cur + mrow * 512;
      const int sw = mrow & 7;
      f32x16 acc = 0.f;
      __builtin_amdgcn_s_setprio(1);
#pragma unroll
      for (int ks = 0; ks < 16; ++ks) {
        bf16x8 b = *(const bf16x8*)(bbase + (((ks * 2 + h) ^ sw) << 4));
        acc = __builtin_amdgcn_mfma_f32_32x32x16_bf16(aq[ks], b, acc, 0, 0, 0);
      }
      __builtin_amdgcn_s_setprio(0);
      const int tm = mt * 2 + msub;
#pragma unroll
      for (int r = 0; r < 16; ++r) {
        const int qrow = (r & 3) + 8 * (r >> 2) + 4 * h;
        const float e = __expf(acc[r]);
        part[r] += e;
        p_e[(size_t)(qw + qrow) * MM + tm * 32 + q5] = f32_to_bf16_rtne(e);
      }
    }
    __syncthreads();
  }

#pragma unroll
  for (int r = 0; r < 16; ++r) {
    float p = part[r];
    p += __shfl_xor(p, 1, 64);
    p += __shfl_xor(p, 2, 64);
    p += __shfl_xor(p, 4, 64);
    p += __shfl_xor(p, 8, 64);
    p += __shfl_xor(p, 16, 64);
    if (q5 == 0) sums[qw + (r & 3) + 8 * (r >> 2) + 4 * h] = p;
  }
}

// ---- Pass 2 (R5 + tm-pairs + p_e reg-prefetch) ----
// 512 blocks x 4 waves x 32q. 32 steps; each stages 2 memT tiles (32KB,
// dbuf 2x32KB) and prefetches next pair's p_e frags into registers a full
// step early. Address paths identical to R5.
__global__ __launch_bounds__(256, 2) void pass2_kernel(
    const u16* __restrict__ p_e, const u16* __restrict__ memTswz,
    const float* __restrict__ sums, float* __restrict__ outO,
    float* __restrict__ outW) {
  __shared__ __align__(16) char tstage[2][32768];

  const int tid = threadIdx.x;
  const int wv = tid >> 6;
  const int l = tid & 63;
  const int q5 = l & 31;
  const int h = l >> 5;
  const int qw = blockIdx.x * 128 + wv * 32;

  const float inv_lane = 1.0f / sums[qw + q5];
  float invr[16];
#pragma unroll
  for (int r = 0; r < 16; ++r) {
    invr[r] = __shfl(inv_lane, (r & 3) + 8 * (r >> 2) + 4 * h, 64);
  }

  auto STAGE2T = [&](int pr, char* buf) {  // tiles 2pr, 2pr+1 -> 32KB linear
#pragma unroll
    for (int i = 0; i < 8; ++i) {
      const int ci = wv * 8 + i;  // 1KB chunks 0..31
      GLOAD16(memTswz + ((size_t)pr * 2048 + ci * 64 + l) * 8,
              buf + (ci << 10));
    }
  };

  const u16* prow_base = p_e + (size_t)(qw + q5) * MM;
  u16x8 pec[4], pen[4];  // [tmi*2 + ks2], current / next pair
#pragma unroll
  for (int j = 0; j < 4; ++j) {
    pec[j] = *(const u16x8*)(prow_base + (j >> 1) * 32 + (j & 1) * 16 + h * 8);
  }

  f32x16 oacc[8];
#pragma unroll
  for (int i = 0; i < 8; ++i) oacc[i] = 0.f;

  STAGE2T(0, tstage[0]);
  __syncthreads();
  for (int pr = 0; pr < 32; ++pr) {
    char* cur = tstage[pr & 1];
    char* nxt = tstage[(pr & 1) ^ 1];
    if (pr + 1 < 32) {
      STAGE2T(pr + 1, nxt);
      const u16* prow = prow_base + (pr + 1) * 64;
#pragma unroll
      for (int j = 0; j < 4; ++j) {
        pen[j] = *(const u16x8*)(prow + (j >> 1) * 32 + (j & 1) * 16 + h * 8);
      }
    }

#pragma unroll
    for (int tmi = 0; tmi < 2; ++tmi) {
      const char* ct = cur + tmi * 16384;
      // W = f32(e)*inv, coalesced float4 stores (identity addressing)
#pragma unroll
      for (int ks2 = 0; ks2 < 2; ++ks2) {
        const u16x8 pe = pec[tmi * 2 + ks2];
        float w[8];
#pragma unroll
        for (int j = 0; j < 8; ++j) {
          w[j] = __builtin_bit_cast(float, (u32)pe[j] << 16) * inv_lane;
        }
        float* base = outW + (size_t)(qw + q5) * MM + (pr * 2 + tmi) * 32 +
                      ks2 * 16 + h * 8;
        *(float4*)base = make_float4(w[0], w[1], w[2], w[3]);
        *(float4*)(base + 4) = make_float4(w[4], w[5], w[6], w[7]);
      }
      __builtin_amdgcn_s_setprio(1);
#pragma unroll
      for (int ks2 = 0; ks2 < 2; ++ks2) {
        const bf16x8 pa = __builtin_bit_cast(bf16x8, pec[tmi * 2 + ks2]);
#pragma unroll
        for (int dsub = 0; dsub < 8; ++dsub) {
          const int d = dsub * 32 + q5;
          const int slot = (2 * ks2 + h) ^ ((d >> 1) & 3);
          bf16x8 b = *(const bf16x8*)(ct + d * 64 + slot * 16);
          oacc[dsub] = __builtin_amdgcn_mfma_f32_32x32x16_bf16(pa, b,
                                                               oacc[dsub], 0,
                                                               0, 0);
        }
      }
      __builtin_amdgcn_s_setprio(0);
    }
    __syncthreads();
#pragma unroll
    for (int j = 0; j < 4; ++j) pec[j] = pen[j];
  }

#pragma unroll
  for (int dsub = 0; dsub < 8; ++dsub) {
#pragma unroll
    for (int r = 0; r < 16; ++r) {
      const int qrow = (r & 3) + 8 * (r >> 2) + 4 * h;
      outO[(size_t)(qw + qrow) * DD + dsub * 32 + q5] = oacc[dsub][r] * invr[r];
    }
  }
}

// ---- Fallback (ws too small): f32-roundtrip via outW (R4/R5-validated) ----
__global__ __launch_bounds__(256, 2) void pass1_fb(
    const float* __restrict__ x, const u16* __restrict__ memb,
    float* __restrict__ outWf, float* __restrict__ sums) {
  __shared__ __align__(16) char stage[2][32768];
  const int tid = threadIdx.x;
  const int wv = tid >> 6;
  const int l = tid & 63;
  const int q5 = l & 31;
  const int h = l >> 5;
  const int qw = blockIdx.x * 128 + wv * 32;

  bf16x8 aq[16];
  {
    const float* xrow = x + (size_t)(qw + q5) * DD;
#pragma unroll
    for (int ks = 0; ks < 16; ++ks) {
      const float4 f0 = *(const float4*)(xrow + ks * 16 + h * 8);
      const float4 f1 = *(const float4*)(xrow + ks * 16 + h * 8 + 4);
      bf16x8 a;
      a[0] = (__bf16)f0.x; a[1] = (__bf16)f0.y;
      a[2] = (__bf16)f0.z; a[3] = (__bf16)f0.w;
      a[4] = (__bf16)f1.x; a[5] = (__bf16)f1.y;
      a[6] = (__bf16)f1.z; a[7] = (__bf16)f1.w;
      aq[ks] = a;
    }
  }
  auto STAGE1 = [&](int mt, char* buf) {
#pragma unroll
    for (int i = 0; i < 8; ++i) {
      const int wc = wv * 8 + i;
      const int row = wc * 2 + h;
      const int csrc = q5 ^ (row & 7);
      GLOAD16(memb + (((size_t)(mt * 64 + row)) << 8) + csrc * 8,
              buf + (wc << 10));
    }
  };
  float part[16];
#pragma unroll
  for (int r = 0; r < 16; ++r) part[r] = 0.f;
  STAGE1(0, stage[0]);
  __syncthreads();
  for (int mt = 0; mt < 32; ++mt) {
    char* cur = stage[mt & 1];
    char* nxt = stage[(mt & 1) ^ 1];
    if (mt + 1 < 32) STAGE1(mt + 1, nxt);
#pragma unroll
    for (int msub = 0; msub < 2; ++msub) {
      const int mrow = msub * 32 + q5;
      const char* bbase = cur + mrow * 512;
      const int sw = mrow & 7;
      f32x16 acc = 0.f;
#pragma unroll
      for (int ks = 0; ks < 16; ++ks) {
        bf16x8 b = *(const bf16x8*)(bbase + (((ks * 2 + h) ^ sw) << 4));
        acc = __builtin_amdgcn_mfma_f32_32x32x16_bf16(aq[ks], b, acc, 0, 0, 0);
      }
      const int tm = mt * 2 + msub;
#pragma unroll
      for (int r = 0; r < 16; ++r) {
        const int qrow = (r & 3) + 8 * (r >> 2) + 4 * h;
        const float e = __expf(acc[r]);
        part[r] += e;
        outWf[(size_t)(qw + qrow) * MM + tm * 32 + q5] = e;
      }
    }
    __syncthreads();
  }
#pragma unroll
  for (int r = 0; r < 16; ++r) {
    float s = part[r];
    s += __shfl_xor(s, 1, 64);
    s += __shfl_xor(s, 2, 64);
    s += __shfl_xor(s, 4, 64);
    s += __shfl_xor(s, 8, 64);
    s += __shfl_xor(s, 16, 64);
    if (q5 == 0) sums[qw + (r & 3) + 8 * (r >> 2) + 4 * h] = s;
  }
}

__global__ __launch_bounds__(256, 2) void pass2_fb(
    const u16* __restrict__ memTswz, const float* __restrict__ sums,
    float* __restrict__ outO, float* __restrict__ outW) {
  __shared__ __align__(16) char tstage[2][16384];
  const int tid = threadIdx.x;
  const int wv = tid >> 6;
  const int l = tid & 63;
  const int q5 = l & 31;
  const int h = l >> 5;
  const int qw = blockIdx.x * 128 + wv * 32;
  const float inv_lane = 1.0f / sums[qw + q5];
  auto STAGE = [&](int t, char* buf) {
#pragma unroll
    for (int i = 0; i < 4; ++i) {
      const int ci = wv * 4 + i;
      GLOAD16(memTswz + ((size_t)t * 1024 + ci * 64 + l) * 8, buf + (ci << 10));
    }
  };
  f32x16 oacc[8];
#pragma unroll
  for (int i = 0; i < 8; ++i) oacc[i] = 0.f;
  STAGE(0, tstage[0]);
  __syncthreads();
  for (int tm = 0; tm < 64; ++tm) {
    char* cur = tstage[tm & 1];
    char* nxt = tstage[(tm & 1) ^ 1];
    if (tm + 1 < 64) STAGE(tm + 1, nxt);
    float* wrow = outW + (size_t)(qw + q5) * MM + tm * 32;
    bf16x8 pa[2];
#pragma unroll
    for (int ks2 = 0; ks2 < 2; ++ks2) {
      float4 f0 = *(const float4*)(wrow + ks2 * 16 + h * 8);
      float4 f1 = *(const float4*)(wrow + ks2 * 16 + h * 8 + 4);
      float w0 = f0.x * inv_lane, w1 = f0.y * inv_lane;
      float w2 = f0.z * inv_lane, w3 = f0.w * inv_lane;
      float w4 = f1.x * inv_lane, w5 = f1.y * inv_lane;
      float w6 = f1.z * inv_lane, w7 = f1.w * inv_lane;
      *(float4*)(wrow + ks2 * 16 + h * 8) = make_float4(w0, w1, w2, w3);
      *(float4*)(wrow + ks2 * 16 + h * 8 + 4) = make_float4(w4, w5, w6, w7);
      bf16x8 p;
      p[0] = (__bf16)w0; p[1] = (__bf16)w1; p[2] = (__bf16)w2;
      p[3] = (__bf16)w3; p[4] = (__bf16)w4; p[5] = (__bf16)w5;
      p[6] = (__bf16)w6; p[7] = (__bf16)w7;
      pa[ks2] = p;
    }
#pragma unroll
    for (int ks2 = 0; ks2 < 2; ++ks2) {
#pragma unroll
      for (int dsub = 0; dsub < 8; ++dsub) {
        const int d = dsub * 32 + q5;
        const int slot = (2 * ks2 + h) ^ ((d >> 1) & 3);
        bf16x8 b = *(const bf16x8*)(cur + d * 64 + slot * 16);
        oacc[dsub] =
            __builtin_amdgcn_mfma_f32_32x32x16_bf16(pa[ks2], b, oacc[dsub], 0,
                                                    0, 0);
      }
    }
    __syncthreads();
  }
#pragma unroll
  for (int dsub = 0; dsub < 8; ++dsub) {
#pragma unroll
    for (int r = 0; r < 16; ++r) {
      const int qrow = (r & 3) + 8 * (r >> 2) + 4 * h;
      outO[(size_t)(qw + qrow) * DD + dsub * 32 + q5] = oacc[dsub][r];
    }
  }
}

extern "C" void kernel_launch(void* const* d_in, const int* in_sizes, int n_in,
                              void* d_out, int out_size, void* d_ws,
                              size_t ws_size, hipStream_t stream) {
  const float* x = (const float*)d_in[0];
  const float* memory = (const float*)d_in[1];
  float* outO = (float*)d_out;           // [65536][256]
  float* outW = outO + (size_t)NQ * DD;  // [65536][2048]

  // ws layout: memb (1MB) | memTswz (1MB) | sums (256KB) | p_e (256MB bf16)
  u16* memb = (u16*)d_ws;
  u16* memTswz = memb + (size_t)MM * DD;
  float* sums = (float*)(memTswz + (size_t)MM * DD);
  u16* p_e = (u16*)(sums + NQ);
  const size_t need = (size_t)MM * DD * 2 * 2 + (size_t)NQ * 4 +
                      (size_t)NQ * MM * 2;  // ~258.25 MB

  mem_convert_kernel<<<dim3((MM * DD) / 256), dim3(256), 0, stream>>>(
      memory, memb, memTswz);
  if (ws_size >= need) {
    pass1_kernel<<<dim3(NQ / 128), dim3(256), 0, stream>>>(x, memb, p_e, sums);
    pass2_kernel<<<dim3(NQ / 128), dim3(256), 0, stream>>>(p_e, memTswz, sums,
                                                           outO, outW);
  } else {
    pass1_fb<<<dim3(NQ / 128), dim3(256), 0, stream>>>(x, memb, outW, sums);
    pass2_fb<<<dim3(NQ / 128), dim3(256), 0, stream>>>(memTswz, sums, outO,
                                                       outW);
  }
}